// Round 8
// baseline (881.795 us; speedup 1.0000x reference)
//
#include <hip/hip_runtime.h>
#include <math.h>

// Problem constants
//   B=4, NB=2048, NA=NC=1024, D=1024, E=8, H=16, HD=64, TOP_K=2
// R3 lesson: NO lambdas capturing register arrays in hot kernels (scratch spills).
// R4 lesson: transpose-store staging maps must be checked for bank collapse.
// R5: GEMMs on bf16 split-3 MFMA (hi*hi+hi*lo+lo*hi), err ~2^-16 — verified safe.
// R6: attention on split-3 MFMA. No-max softmax (scores bounded ~2.4, exp safe).
// R7 LESSON: forcing occupancy past natural reg demand -> catastrophic spill.
// R8 LESSON: swizzles must be audited mod-32 PER ACCESS WIDTH.
// R9: single barrier/kt + dbuf K,V via global_load_lds (good for attn).
// R10: swapped-operand attention: S^T = mfma32(K_frag, Q_frag); exp(S^T) regs
//     ARE the P^T B-frag -> PV from regs, no P LDS. 246us.
// R11 LESSON: async+1-barrier GEMM REGRESSED (-40us total): next-tile DMA drain
//     coupled to same-iter compute (~500cy) < HBM latency (~900cy) -> exposed
//     every step. Reverted to reg-staged 2-barrier bfgemm (820us config).
// R12: PV on legacy mfma16 (half-rate / asm-volatile suspect) -> paired-jt
//     mfma32: concat P^T frags of jt,jt+1 (shufflevector) as K=32 B-operand;
//     concat matching V sh4 pair as A. Same slot->k permutation both sides
//     (bijection re-audited R7-round). 96 mfma16 -> 48 mfma32/kt, all builtins.
// R7(bench): container failed twice (infra) — R12 never measured; resubmitted.

typedef __attribute__((ext_vector_type(8))) short short8;
typedef __attribute__((ext_vector_type(4))) short sh4;
typedef __attribute__((ext_vector_type(4))) float f32x4;
typedef __attribute__((ext_vector_type(4))) unsigned int u32x4;
typedef unsigned short u16;
typedef unsigned int u32;

// ----------------------------------------------------------------------------
__global__ void zero_k(double* p) {
    if (threadIdx.x < 8) p[threadIdx.x] = 0.0;
}

// ----------------------------------------------------------------------------
// fp32 -> bf16 hi/lo split helpers (RNE)
__device__ inline u16 bf_hi(float x) {
    u32 u = __float_as_uint(x);
    u += 0x7FFFu + ((u >> 16) & 1u);
    return (u16)(u >> 16);
}
__device__ inline u16 bf_lo(float x, u16 h) {
    float hf = __uint_as_float(((u32)h) << 16);
    return bf_hi(x - hf);
}
__device__ inline u32 pack_bf(float x) {
    u32 u = __float_as_uint(x);
    u32 hi = (u + (0x7FFFu + ((u >> 16) & 1u))) >> 16;
    float hf = __uint_as_float(hi << 16);
    float d = x - hf;
    u32 u2 = __float_as_uint(d);
    u32 lo = (u2 + (0x7FFFu + ((u2 >> 16) & 1u))) >> 16;
    return (hi << 16) | lo;
}

// fast pair-pack: two fp32 -> two (hi<<16|lo) u32 via v_cvt_pk_bf16_f32 + v_perm.
__device__ inline void pack2(float p0, float p1, u32& o0, u32& o1) {
    u32 h01, l01;
    asm("v_cvt_pk_bf16_f32 %0, %1, %2" : "=v"(h01) : "v"(p0), "v"(p1));
    float d0 = p0 - __uint_as_float(h01 << 16);
    float d1 = p1 - __uint_as_float(h01 & 0xffff0000u);
    asm("v_cvt_pk_bf16_f32 %0, %1, %2" : "=v"(l01) : "v"(d0), "v"(d1));
    o0 = __builtin_amdgcn_perm(h01, l01, 0x05040100u);   // [h0|l0]
    o1 = __builtin_amdgcn_perm(h01, l01, 0x07060302u);   // [h1|l1]
}

// exp2 of 4 scores -> split-3 bf16 P^T fragments (hi, lo) + lsum accumulate.
__device__ inline void pfrag(const f32x4 s, sh4& hi, sh4& lo, float& acc) {
    float p0 = exp2f(s[0]), p1 = exp2f(s[1]), p2 = exp2f(s[2]), p3 = exp2f(s[3]);
    acc += (p0 + p1) + (p2 + p3);
    u32 h01, h23, l01, l23;
    asm("v_cvt_pk_bf16_f32 %0, %1, %2" : "=v"(h01) : "v"(p0), "v"(p1));
    asm("v_cvt_pk_bf16_f32 %0, %1, %2" : "=v"(h23) : "v"(p2), "v"(p3));
    float d0 = p0 - __uint_as_float(h01 << 16);
    float d1 = p1 - __uint_as_float(h01 & 0xffff0000u);
    float d2 = p2 - __uint_as_float(h23 << 16);
    float d3 = p3 - __uint_as_float(h23 & 0xffff0000u);
    asm("v_cvt_pk_bf16_f32 %0, %1, %2" : "=v"(l01) : "v"(d0), "v"(d1));
    asm("v_cvt_pk_bf16_f32 %0, %1, %2" : "=v"(l23) : "v"(d2), "v"(d3));
    union { u32 u[2]; sh4 s4; } H, L;
    H.u[0] = h01; H.u[1] = h23;
    L.u[0] = l01; L.u[1] = l23;
    hi = H.s4; lo = L.s4;
}

__device__ inline f32x4 mfma32(short8 a, short8 b, f32x4 c) {
    return __builtin_amdgcn_mfma_f32_16x16x32_bf16(a, b, c, 0, 0, 0);
}

// async global->LDS, 16B per lane. LDS dest = wave-uniform base + lane*16.
__device__ inline void async16(const u16* g, u16* l) {
    __builtin_amdgcn_global_load_lds(
        (const __attribute__((address_space(1))) unsigned int*)g,
        (__attribute__((address_space(3))) unsigned int*)l,
        16, 0, 0);
}

__global__ __launch_bounds__(256)
void split_k(const float* __restrict__ in, u16* __restrict__ hi,
             u16* __restrict__ lo, int n4) {
    int i = blockIdx.x * 256 + threadIdx.x;
    if (i >= n4) return;
    float4 x = ((const float4*)in)[i];
    ushort4 h, l;
    h.x = bf_hi(x.x); l.x = bf_lo(x.x, h.x);
    h.y = bf_hi(x.y); l.y = bf_lo(x.y, h.y);
    h.z = bf_hi(x.z); l.z = bf_lo(x.z, h.z);
    h.w = bf_hi(x.w); l.w = bf_lo(x.w, h.w);
    ((ushort4*)hi)[i] = h;
    ((ushort4*)lo)[i] = l;
}

// ----------------------------------------------------------------------------
__global__ void emb_k(const int* __restrict__ t, float* __restrict__ emb) {
    int b = blockIdx.x;
    int j = threadIdx.x; // 0..511
    float x1 = (float)(-9.210340371976184) * (float)j;
    float x2 = x1 / 511.0f;
    float freq = (float)exp((double)x2);
    float tf = (float)t[b];
    float arg = tf * freq;
    emb[b * 1024 + j]       = (float)sin((double)arg);
    emb[b * 1024 + 512 + j] = (float)cos((double)arg);
}

// ----------------------------------------------------------------------------
__global__ void te_fc_k(const float* __restrict__ in, const float* __restrict__ W,
                        const float* __restrict__ bias, float* __restrict__ out,
                        int K, int N, int do_silu) {
    int b = blockIdx.x;
    int wv = threadIdx.x >> 6, lane = threadIdx.x & 63;
    const float* inb = in + (size_t)b * K;
    int n0 = blockIdx.y * 16 + wv * 4;
    for (int q = 0; q < 4; q++) {
        int n = n0 + q;
        const float* wr = W + (size_t)n * K;
        float acc = 0.f;
        for (int c = lane * 4; c < K; c += 256) {
            float4 a  = *(const float4*)(inb + c);
            float4 w4 = *(const float4*)(wr + c);
            acc += a.x * w4.x + a.y * w4.y + a.z * w4.z + a.w * w4.w;
        }
#pragma unroll
        for (int off = 1; off < 64; off <<= 1) acc += __shfl_xor(acc, off, 64);
        if (lane == 0) {
            float x = acc + bias[n];
            out[(size_t)b * N + n] = do_silu ? (x / (1.0f + expf(-x))) : x;
        }
    }
}

// ----------------------------------------------------------------------------
// bf16 split-3 MFMA GEMM (R10 reg-staged form — R11 async variant regressed).
// C[rr,cc] = (dot(A[rr,:K], W[cc,:K]) + bias) * scale.
// OMODE: 0 = fp32 out (identity rows), 1 = bf16 hi/lo planes (identity),
//        2 = bf16 planes with KV row remap (K proj), 3 = transposed V^T planes
//        (rows = v-col, cols = act rows; bias indexed by ROW).
template<bool GATE, bool RELU, int OMODE>
__global__ __launch_bounds__(256, 2)
void bfgemm_k(const u16* __restrict__ A0h, const u16* __restrict__ A0l,
              const u16* __restrict__ A1h, const u16* __restrict__ A1l,
              const u16* __restrict__ A2h, const u16* __restrict__ A2l,
              const u16* __restrict__ Wh_g, const u16* __restrict__ Wl_g,
              const float* __restrict__ bias, float* __restrict__ C,
              u16* __restrict__ Chi, u16* __restrict__ Clo, int K, float scale)
{
    __shared__ u16 Ah[128 * 32];
    __shared__ u16 Al[128 * 32];
    __shared__ u16 Wh[128 * 32];
    __shared__ u16 Wl[128 * 32];
    const int tid = threadIdx.x;
    const int row0 = blockIdx.x * 128;
    const int col0 = blockIdx.y * 128;
    const int wv = tid >> 6;
    const int lane = tid & 63;
    const int wrow = (wv & 1) * 64;
    const int wcol = (wv >> 1) * 64;
    const int l15 = lane & 15, quad = lane >> 4;

    f32x4 acc[4][4];
#pragma unroll
    for (int i = 0; i < 4; i++)
#pragma unroll
        for (int j = 0; j < 4; j++)
            acc[i][j] = (f32x4){0.f, 0.f, 0.f, 0.f};

    const int ar0 = tid >> 2, ak0 = (tid & 3) * 8;
    const int ar1 = (tid + 256) >> 2, ak1 = ((tid + 256) & 3) * 8;

    for (int kc = 0; kc < K; kc += 32) {
        const u16* pAh = A0h;
        const u16* pAl = A0l;
        int kk = kc;
        int tembseg = 0;
        if (GATE) {
            int seg = kc >> 10;
            if (seg == 1) { pAh = A1h; pAl = A1l; }
            else if (seg == 2) { pAh = A2h; pAl = A2l; tembseg = 1; }
            kk = kc & 1023;
        }
        const int astr = GATE ? 1024 : K;
        int g0 = row0 + ar0, g1 = row0 + ar1;
        if (GATE && tembseg) { g0 >>= 11; g1 >>= 11; }
        uint4 vah0 = *(const uint4*)&pAh[(size_t)g0 * astr + kk + ak0];
        uint4 vah1 = *(const uint4*)&pAh[(size_t)g1 * astr + kk + ak1];
        uint4 val0 = *(const uint4*)&pAl[(size_t)g0 * astr + kk + ak0];
        uint4 val1 = *(const uint4*)&pAl[(size_t)g1 * astr + kk + ak1];
        uint4 vwh0 = *(const uint4*)&Wh_g[(size_t)(col0 + ar0) * K + kc + ak0];
        uint4 vwh1 = *(const uint4*)&Wh_g[(size_t)(col0 + ar1) * K + kc + ak1];
        uint4 vwl0 = *(const uint4*)&Wl_g[(size_t)(col0 + ar0) * K + kc + ak0];
        uint4 vwl1 = *(const uint4*)&Wl_g[(size_t)(col0 + ar1) * K + kc + ak1];
        __syncthreads();
        *(uint4*)&Ah[ar0 * 32 + ak0] = vah0;
        *(uint4*)&Ah[ar1 * 32 + ak1] = vah1;
        *(uint4*)&Al[ar0 * 32 + ak0] = val0;
        *(uint4*)&Al[ar1 * 32 + ak1] = val1;
        *(uint4*)&Wh[ar0 * 32 + ak0] = vwh0;
        *(uint4*)&Wh[ar1 * 32 + ak1] = vwh1;
        *(uint4*)&Wl[ar0 * 32 + ak0] = vwl0;
        *(uint4*)&Wl[ar1 * 32 + ak1] = vwl1;
        __syncthreads();

        short8 a_h[4], a_l[4];
#pragma unroll
        for (int i = 0; i < 4; i++) {
            int r = (wrow + i * 16 + l15) * 32 + quad * 8;
            a_h[i] = *(const short8*)&Ah[r];
            a_l[i] = *(const short8*)&Al[r];
        }
#pragma unroll
        for (int j = 0; j < 4; j++) {
            int c = (wcol + j * 16 + l15) * 32 + quad * 8;
            short8 b_h = *(const short8*)&Wh[c];
            short8 b_l = *(const short8*)&Wl[c];
#pragma unroll
            for (int i = 0; i < 4; i++) {
                acc[i][j] = __builtin_amdgcn_mfma_f32_16x16x32_bf16(a_h[i], b_h, acc[i][j], 0, 0, 0);
                acc[i][j] = __builtin_amdgcn_mfma_f32_16x16x32_bf16(a_h[i], b_l, acc[i][j], 0, 0, 0);
                acc[i][j] = __builtin_amdgcn_mfma_f32_16x16x32_bf16(a_l[i], b_h, acc[i][j], 0, 0, 0);
            }
        }
    }

#pragma unroll
    for (int i = 0; i < 4; i++) {
#pragma unroll
        for (int j = 0; j < 4; j++) {
            int cc = col0 + wcol + j * 16 + l15;
#pragma unroll
            for (int r = 0; r < 4; r++) {
                int rr = row0 + wrow + i * 16 + quad * 4 + r;
                float v = (acc[i][j][r] + ((OMODE == 3) ? bias[rr] : bias[cc])) * scale;
                if (RELU) v = fmaxf(v, 0.f);
                if (OMODE == 0) {
                    C[(size_t)rr * 1024 + cc] = v;
                } else if (OMODE == 1) {
                    u32 pk = pack_bf(v);
                    size_t a = (size_t)rr * 1024 + cc;
                    Chi[a] = (u16)(pk >> 16); Clo[a] = (u16)pk;
                } else if (OMODE == 2) {
                    int orow = ((rr >> 10) & 3) * 2048 + (rr >> 12) * 1024 + (rr & 1023);
                    u32 pk = pack_bf(v);
                    size_t a = (size_t)orow * 1024 + cc;
                    Chi[a] = (u16)(pk >> 16); Clo[a] = (u16)pk;
                } else {
                    int bb2 = (cc >> 10) & 3;
                    int key = (cc >> 12) * 1024 + (cc & 1023);
                    u32 pk = pack_bf(v);
                    size_t a = ((size_t)(bb2 * 1024 + rr)) * 2048 + key;
                    Chi[a] = (u16)(pk >> 16); Clo[a] = (u16)pk;
                }
            }
        }
    }
}

// ----------------------------------------------------------------------------
// MFMA flash attention, split-3 bf16, no-max softmax, swapped operands.
// Block: 512 thr (8 waves), q-tile 256 (32 q/wave), k-tile 64, 32 k-steps.
// LDS 65536 B (2 blocks/CU): K,V tiles double-buffered, chunk-XOR swizzled.
// S^T = mfma32(A=K_frag, B=Q_frag); exp(S^T) regs are the P^T fragments.
// PV (R12): jt-tiles paired -> K=32 mfma32; A = concat(V sh4 of jt0,jt1),
// B = concat(P^T frag of jt0,jt1). Same slot->k bijection both operands.
__global__ __launch_bounds__(512, 4)
void attn_k(const u16* Qh, const u16* Ql,
            const u16* __restrict__ Kh, const u16* __restrict__ Kl,
            const u16* __restrict__ Vh, const u16* __restrict__ Vl,
            u16* Oh, u16* Ol)
{
    __shared__ __align__(16) u16 smem[32768];   // 64 KB
    u16* Kbase = smem;              // [buf:2][plane:2][4096]
    u16* Vbase = smem + 16384;      // [buf:2][plane:2][4096]

    const int tid = threadIdx.x;
    const int w = tid >> 6, lane = tid & 63;
    const int l15 = lane & 15, quad = lane >> 4;
    const int bh = blockIdx.x, b = bh >> 4, h = bh & 15;
    const int qw = blockIdx.y * 256 + w * 32;          // local q base of this wave
    const int qrow0 = b * 2048 + qw;                    // global Q plane row base

    // Q fragments in registers (B-operand = Q^T of the swapped QK^T)
    short8 qh_f[2][2], ql_f[2][2];
#pragma unroll
    for (int i = 0; i < 2; i++)
#pragma unroll
        for (int kc = 0; kc < 2; kc++) {
            size_t a = (size_t)(qrow0 + i * 16 + l15) * 1024 + h * 64 + kc * 32 + quad * 8;
            qh_f[i][kc] = *(const short8*)&Qh[a];
            ql_f[i][kc] = *(const short8*)&Ql[a];
        }

    // staging maps: linear LDS dest (wave base + lane*16); global source column
    // carries the chunk swizzle c8 ^ (row&7). 512 thr cover a 64-row tile/plane.
    const int srow = tid >> 3;                        // 0..63
    const int scsw = ((tid & 7) ^ (srow & 7)) << 3;   // swizzled u16 col
    const size_t gk_base = ((size_t)(b * 2048) + srow) * 1024 + h * 64 + scsw;
    const size_t gv_base = ((size_t)((b * 16 + h) * 64 + srow)) * 2048 + scsw;

    f32x4 o[4][2];                 // O^T accumulators: [d-tile][q-subtile]
#pragma unroll
    for (int dt = 0; dt < 4; dt++)
#pragma unroll
        for (int i = 0; i < 2; i++) o[dt][i] = (f32x4){0.f, 0.f, 0.f, 0.f};
    float lsum[2] = {0.f, 0.f};

    // prologue: stage tile 0 into buf 0
    {
        u16* kd = Kbase + w * 512;
        u16* vd = Vbase + w * 512;
        async16(&Kh[gk_base], kd);
        async16(&Kl[gk_base], kd + 4096);
        async16(&Vh[gv_base], vd);
        async16(&Vl[gv_base], vd + 4096);
    }
    __syncthreads();   // vmcnt drained before barrier -> tile 0 ready

    for (int kt = 0; kt < 32; kt++) {
        const int cur = kt & 1;
        if (kt < 31) {
            const int nxt = cur ^ 1;
            const size_t gk = gk_base + (size_t)(kt + 1) * 65536;  // +64 keys
            const size_t gv = gv_base + (size_t)(kt + 1) * 64;     // +64 key-cols
            u16* kd = Kbase + nxt * 8192 + w * 512;
            u16* vd = Vbase + nxt * 8192 + w * 512;
            async16(&Kh[gk], kd);
            async16(&Kl[gk], kd + 4096);
            async16(&Vh[gv], vd);
            async16(&Vl[gv], vd + 4096);
        }
        const u16* Ksh = Kbase + cur * 8192;
        const u16* Ksl = Ksh + 4096;
        const u16* Vsh = Vbase + cur * 8192;
        const u16* Vsl = Vsh + 4096;

#pragma unroll
        for (int jp = 0; jp < 2; jp++) {
            // QK^T for the two jt's of this pair; P^T frags held in regs
            sh4 phi[2][2], plo[2][2];      // [js][q-subtile]
#pragma unroll
            for (int js = 0; js < 2; js++) {
                const int jt = jp * 2 + js;
                f32x4 st0 = (f32x4){0.f, 0.f, 0.f, 0.f};
                f32x4 st1 = (f32x4){0.f, 0.f, 0.f, 0.f};
                const int ka = (jt * 16 + l15) * 64 + ((quad ^ (l15 & 7)) << 3);
                short8 kh0 = *(const short8*)&Ksh[ka];
                short8 kh1 = *(const short8*)&Ksh[ka ^ 32];
                short8 kl0 = *(const short8*)&Ksl[ka];
                short8 kl1 = *(const short8*)&Ksl[ka ^ 32];
                st0 = mfma32(kh0, qh_f[0][0], st0);
                st0 = mfma32(kl0, qh_f[0][0], st0);
                st0 = mfma32(kh0, ql_f[0][0], st0);
                st0 = mfma32(kh1, qh_f[0][1], st0);
                st0 = mfma32(kl1, qh_f[0][1], st0);
                st0 = mfma32(kh1, ql_f[0][1], st0);
                st1 = mfma32(kh0, qh_f[1][0], st1);
                st1 = mfma32(kl0, qh_f[1][0], st1);
                st1 = mfma32(kh0, ql_f[1][0], st1);
                st1 = mfma32(kh1, qh_f[1][1], st1);
                st1 = mfma32(kl1, qh_f[1][1], st1);
                st1 = mfma32(kh1, ql_f[1][1], st1);
                pfrag(st0, phi[js][0], plo[js][0], lsum[0]);
                pfrag(st1, phi[js][1], plo[js][1], lsum[1]);
            }
            // PV: paired-jt K=32 mfma32. V chunk addressing identical to the
            // per-jt sh4 loads (chunk = jt*2 + (quad>>1), XOR l15&7 swizzle).
#pragma unroll
            for (int dt = 0; dt < 4; dt++) {
                const int x = l15 & 7;
                const int basep = (dt * 16 + l15) * 64 + (quad & 1) * 4;
                const int ch0 = jp * 4 + (quad >> 1);
                const int ch1 = ch0 + 2;
                sh4 vh0 = *(const sh4*)&Vsh[basep + ((ch0 ^ x) << 3)];
                sh4 vh1 = *(const sh4*)&Vsh[basep + ((ch1 ^ x) << 3)];
                sh4 vl0 = *(const sh4*)&Vsl[basep + ((ch0 ^ x) << 3)];
                sh4 vl1 = *(const sh4*)&Vsl[basep + ((ch1 ^ x) << 3)];
                short8 VH = __builtin_shufflevector(vh0, vh1, 0, 1, 2, 3, 4, 5, 6, 7);
                short8 VL = __builtin_shufflevector(vl0, vl1, 0, 1, 2, 3, 4, 5, 6, 7);
#pragma unroll
                for (int i = 0; i < 2; i++) {
                    short8 PH = __builtin_shufflevector(phi[0][i], phi[1][i], 0, 1, 2, 3, 4, 5, 6, 7);
                    short8 PL = __builtin_shufflevector(plo[0][i], plo[1][i], 0, 1, 2, 3, 4, 5, 6, 7);
                    o[dt][i] = mfma32(VH, PH, o[dt][i]);
                    o[dt][i] = mfma32(VL, PH, o[dt][i]);
                    o[dt][i] = mfma32(VH, PL, o[dt][i]);
                }
            }
        }
        __syncthreads();   // all reads of buf[cur] done; DMA(kt+1) drained
    }

    // lsum: sum over k -> reduce across the 4 quads (q = i*16+l15 per lane)
#pragma unroll
    for (int i = 0; i < 2; i++) {
        float s2 = lsum[i];
        s2 += __shfl_xor(s2, 16, 64);
        s2 += __shfl_xor(s2, 32, 64);
        lsum[i] = 1.0f / s2;
    }

    // epilogue: O^T -> O via in-LDS transpose (aliases dead K/V region; the
    // final loop barrier synced all waves). Per-wave 8KB region, XOR-swizzled:
    // write b64 2 lanes/bank, read b128 8 lanes/4-bank group (floor).
    u32* otr = (u32*)smem + w * 2048;
#pragma unroll
    for (int i = 0; i < 2; i++) {
        const int q = i * 16 + l15;
        const int xm = (q & 7) << 2;
#pragma unroll
        for (int dt = 0; dt < 4; dt++) {
#pragma unroll
            for (int r = 0; r < 4; r += 2) {
                float v0 = o[dt][i][r]     * lsum[i];
                float v1 = o[dt][i][r + 1] * lsum[i];
                u32 a0, a1;
                pack2(v0, v1, a0, a1);
                const int d = dt * 16 + quad * 4 + r;
                uint2 val; val.x = a0; val.y = a1;
                *(uint2*)&otr[q * 64 + (d ^ xm)] = val;
            }
        }
    }
    // same-wave read-back (in-wave lgkm ordering suffices)
    const int qr = lane >> 1;      // 0..31
    const int dh = lane & 1;
    const size_t gq = (size_t)(qrow0 + qr) * 1024 + h * 64 + dh * 32;
#pragma unroll
    for (int g = 0; g < 4; g++) {
        const int c0 = dh * 8 + g * 2;
        const int m = qr & 7;
        uint4 x = *(const uint4*)&otr[qr * 64 + ((c0 ^ m) << 2)];
        uint4 y = *(const uint4*)&otr[qr * 64 + (((c0 + 1) ^ m) << 2)];
        union { short8 s; u32x4 u; } hh, ll;
        hh.u = (u32x4){ __builtin_amdgcn_perm(x.y, x.x, 0x07060302u),
                        __builtin_amdgcn_perm(x.w, x.z, 0x07060302u),
                        __builtin_amdgcn_perm(y.y, y.x, 0x07060302u),
                        __builtin_amdgcn_perm(y.w, y.z, 0x07060302u) };
        ll.u = (u32x4){ __builtin_amdgcn_perm(x.y, x.x, 0x05040100u),
                        __builtin_amdgcn_perm(x.w, x.z, 0x05040100u),
                        __builtin_amdgcn_perm(y.y, y.x, 0x05040100u),
                        __builtin_amdgcn_perm(y.w, y.z, 0x05040100u) };
        *(short8*)&Oh[gq + g * 8] = hh.s;
        *(short8*)&Ol[gq + g * 8] = ll.s;
    }
}

// ----------------------------------------------------------------------------
// layernorm(X + T) * g + b, emitting bf16 hi/lo planes for the gate GEMM
__global__ __launch_bounds__(256)
void ln_split_k(const float* __restrict__ X, const float* __restrict__ T,
                const float* __restrict__ g, const float* __restrict__ bta,
                u16* __restrict__ chi, u16* __restrict__ clo)
{
    __shared__ float red[8];
    int r = blockIdx.x, tid = threadIdx.x;
    size_t base = (size_t)r * 1024 + tid * 4;
    float4 x  = *(const float4*)(X + base);
    float4 tk = *(const float4*)(T + base);
    x.x += tk.x; x.y += tk.y; x.z += tk.z; x.w += tk.w;
    float s = x.x + x.y + x.z + x.w;
#pragma unroll
    for (int off = 1; off < 64; off <<= 1) s += __shfl_xor(s, off, 64);
    int wv = tid >> 6;
    if ((tid & 63) == 0) red[wv] = s;
    __syncthreads();
    float mu = (red[0] + red[1] + red[2] + red[3]) * (1.0f / 1024.0f);
    float dx0 = x.x - mu, dx1 = x.y - mu, dx2 = x.z - mu, dx3 = x.w - mu;
    float ss = dx0 * dx0 + dx1 * dx1 + dx2 * dx2 + dx3 * dx3;
#pragma unroll
    for (int off = 1; off < 64; off <<= 1) ss += __shfl_xor(ss, off, 64);
    if ((tid & 63) == 0) red[4 + wv] = ss;
    __syncthreads();
    float var = (red[4] + red[5] + red[6] + red[7]) * (1.0f / 1024.0f);
    float inv = 1.0f / sqrtf(var + 1e-5f);
    float4 gg = *(const float4*)(g + tid * 4);
    float4 bb = *(const float4*)(bta + tid * 4);
    float y0 = dx0 * inv * gg.x + bb.x;
    float y1 = dx1 * inv * gg.y + bb.y;
    float y2 = dx2 * inv * gg.z + bb.z;
    float y3 = dx3 * inv * gg.w + bb.w;
    ushort4 h, l;
    h.x = bf_hi(y0); l.x = bf_lo(y0, h.x);
    h.y = bf_hi(y1); l.y = bf_lo(y1, h.y);
    h.z = bf_hi(y2); l.z = bf_lo(y2, h.z);
    h.w = bf_hi(y3); l.w = bf_lo(y3, h.w);
    *(ushort4*)&chi[base] = h;
    *(ushort4*)&clo[base] = l;
}

// ----------------------------------------------------------------------------
__global__ __launch_bounds__(256)
void logits_k(const float* __restrict__ Hd, const float* __restrict__ W2,
              const float* __restrict__ b2, const float* __restrict__ eb,
              float* __restrict__ Lg)
{
    int gw = (blockIdx.x * 256 + threadIdx.x) >> 6;  // row 0..8191
    int lane = threadIdx.x & 63;
    const float* h = Hd + (size_t)gw * 1024;
    float4 hv[4];
#pragma unroll
    for (int j = 0; j < 4; j++) hv[j] = *(const float4*)(h + j * 256 + lane * 4);
    float res[8];
#pragma unroll
    for (int e = 0; e < 8; e++) {
        const float* w = W2 + (size_t)e * 1024;
        float acc = 0.f;
#pragma unroll
        for (int j = 0; j < 4; j++) {
            float4 w4 = *(const float4*)(w + j * 256 + lane * 4);
            acc += hv[j].x * w4.x + hv[j].y * w4.y + hv[j].z * w4.z + hv[j].w * w4.w;
        }
#pragma unroll
        for (int off = 1; off < 64; off <<= 1) acc += __shfl_xor(acc, off, 64);
        res[e] = acc;
    }
    if (lane < 8) {
        float v = res[0];
#pragma unroll
        for (int e = 1; e < 8; e++) v = (lane == e) ? res[e] : v;
        Lg[(size_t)gw * 8 + lane] = v + b2[lane] + eb[lane];
    }
}

// ----------------------------------------------------------------------------
__global__ __launch_bounds__(256)
void router_k(const float* __restrict__ Lg, const int* __restrict__ t,
              float* __restrict__ outp, double* __restrict__ loadAcc)
{
    __shared__ double wred[4][8];
    int tid = threadIdx.x;
    int r = blockIdx.x * 256 + tid;   // 0..8191
    int b = r >> 11;
    float tn  = (float)t[b] / 1000.0f;
    float tau = 0.5f + 1.5f * tn;
    float p[8];
    float mx = -INFINITY;
#pragma unroll
    for (int e = 0; e < 8; e++) { p[e] = Lg[(size_t)r * 8 + e] / tau; mx = fmaxf(mx, p[e]); }
    float sum = 0.f;
#pragma unroll
    for (int e = 0; e < 8; e++) { p[e] = expf(p[e] - mx); sum += p[e]; }
#pragma unroll
    for (int e = 0; e < 8; e++) p[e] = p[e] / sum;
#pragma unroll
    for (int e = 0; e < 8; e++) p[e] = 0.85f * p[e] + 0.01875f;   // (1-ALPHA)p + ALPHA/E
    float w = 0.1f + 0.1f * tn;
    float shared_p = fmaxf(p[0], w);
    float osum = 0.f;
#pragma unroll
    for (int e = 1; e < 8; e++) osum += p[e];
    float denom_o = fmaxf(osum, 1e-8f);
    float one_m = 1.0f - shared_p;
    p[0] = shared_p;
#pragma unroll
    for (int e = 1; e < 8; e++) p[e] = (p[e] / denom_o) * one_m;  // match np op order
    int i0 = 0; float v0 = p[0];
#pragma unroll
    for (int e = 1; e < 8; e++) if (p[e] > v0) { v0 = p[e]; i0 = e; }
    int i1 = -1; float v1 = -INFINITY;
#pragma unroll
    for (int e = 0; e < 8; e++) if (e != i0 && p[e] > v1) { v1 = p[e]; i1 = e; }
    float cap = 0.5f + 0.1f * tn;
    float dsp[8], capped[8], hr[8];
    float exsum = 0.f, hsum = 0.f;
#pragma unroll
    for (int e = 0; e < 8; e++) {
        float d = ((e == i0) ? v0 : 0.f) + ((e == i1) ? v1 : 0.f);
        float ex = fmaxf(d - cap, 0.f);
        float c = d - ex;
        float hh = fmaxf(cap - c, 0.f);
        capped[e] = c; hr[e] = hh;
        exsum += ex; hsum += hh;
    }
    float hden = fmaxf(hsum, 1e-8f);
    float dsum = 0.f;
#pragma unroll
    for (int e = 0; e < 8; e++) {
        float d = capped[e] + exsum * (hr[e] / hden);
        dsp[e] = d; dsum += d;
    }
    float cden = dsum + 1e-8f;
#pragma unroll
    for (int e = 0; e < 8; e++) {
        outp[(size_t)r * 8 + e] = dsp[e];
        outp[65536 + (size_t)r * 8 + e] = dsp[e] / cden;
    }
    int lane = tid & 63, wv = tid >> 6;
#pragma unroll
    for (int e = 0; e < 8; e++) {
        double s = (double)dsp[e];
#pragma unroll
        for (int off = 1; off < 64; off <<= 1) s += __shfl_xor(s, off, 64);
        if (lane == 0) wred[wv][e] = s;
    }
    __syncthreads();
    if (tid < 8) {
        double s = wred[0][tid] + wred[1][tid] + wred[2][tid] + wred[3][tid];
        atomicAdd(&loadAcc[tid], s);
    }
}

// ----------------------------------------------------------------------------
__global__ void penalty_k(const double* __restrict__ loadAcc, float* __restrict__ outp) {
    if (threadIdx.x == 0) {
        const float thr = (float)(2048.0 / 7.0 * 1.5);  // fair * 1.5
        float pen = 0.f;
#pragma unroll
        for (int e = 1; e < 8; e++) {
            float load = (float)(loadAcc[e] / 4.0);     // mean over B
            float x = fmaxf(load - thr, 0.f);
            pen += x * x;
        }
        outp[131072] = 0.01f * pen;
    }
}

// ----------------------------------------------------------------------------
extern "C" void kernel_launch(void* const* d_in, const int* in_sizes, int n_in,
                              void* d_out, int out_size, void* d_ws, size_t ws_size,
                              hipStream_t stream)
{
    const float* tokens = (const float*)d_in[0];
    const float* outA   = (const float*)d_in[1];
    const float* outC   = (const float*)d_in[2];
    const int*   tt     = (const int*)  d_in[3];
    const float* in_w   = (const float*)d_in[4];
    const float* in_b   = (const float*)d_in[5];
    const float* op_w   = (const float*)d_in[6];
    const float* op_b   = (const float*)d_in[7];
    const float* lng    = (const float*)d_in[8];
    const float* lnb    = (const float*)d_in[9];
    const float* te_w1  = (const float*)d_in[10];
    const float* te_b1  = (const float*)d_in[11];
    const float* te_w2  = (const float*)d_in[12];
    const float* te_b2  = (const float*)d_in[13];
    const float* g_w1   = (const float*)d_in[14];
    const float* g_b1   = (const float*)d_in[15];
    const float* g_w2   = (const float*)d_in[16];
    const float* g_b2   = (const float*)d_in[17];
    const float* e_bias = (const float*)d_in[18];
    float* out = (float*)d_out;

    float* ws = (float*)d_ws;
    const size_t NM = (size_t)8192 * 1024;
    float* F0     = ws;                  // out_proj result, then gate hidden (fp32)
    float* temb   = ws + NM;             // 4x1024 fp32
    float* embb   = temb + 4096;
    float* hte    = embb + 4096;         // 4x2048
    float* logitsb = hte + 8192;         // 8192x8
    double* loads = (double*)(logitsb + 65536);   // 8 doubles (+pad)

    u16* U = (u16*)(loads + 16);
    u16* Tokh = U;                 // tokens planes (alive whole launch)
    u16* Tokl = Tokh + NM;
    u16* ActH = Tokl + NM;         // [outA;outC] planes for K/V GEMMs
    u16* ActL = ActH + NM;
    u16* Qh   = ActL + NM;         // Q planes -> attn ctx planes (block-disjoint alias)
    u16* Ql   = Qh + NM;
    u16* Kh   = Ql + NM;           // K planes -> later LN(ctx_B) planes
    u16* Kl   = Kh + NM;
    u16* Vth  = Kl + NM;           // V^T planes [b][h][d][2048]
    u16* Vtl  = Vth + NM;
    u16* Wsh  = Vtl + NM;          // weight planes (up to 3M elems)
    u16* Wsl  = Wsh + (size_t)3 * 1024 * 1024;
    u16* Tbh  = Wsl + (size_t)3 * 1024 * 1024;   // temb planes, 4096
    u16* Tbl  = Tbh + 4096;

    zero_k<<<1, 64, 0, stream>>>(loads);
    emb_k<<<4, 512, 0, stream>>>(tt, embb);
    te_fc_k<<<dim3(4, 128), 256, 0, stream>>>(embb, te_w1, te_b1, hte, 1024, 2048, 1);
    te_fc_k<<<dim3(4, 64),  256, 0, stream>>>(hte,  te_w2, te_b2, temb, 2048, 1024, 0);

    split_k<<<8192, 256, 0, stream>>>(tokens, Tokh, Tokl, 8192 * 1024 / 4);
    split_k<<<3072, 256, 0, stream>>>(in_w, Wsh, Wsl, 3 * 1024 * 1024 / 4);
    split_k<<<4096, 256, 0, stream>>>(outA, ActH, ActL, 4096 * 1024 / 4);
    split_k<<<4096, 256, 0, stream>>>(outC, ActH + (size_t)4096 * 1024,
                                      ActL + (size_t)4096 * 1024, 4096 * 1024 / 4);

    // q = (tokens @ wq.T + bq) * (0.125*log2e) -> Q planes (softmax scale folded)
    bfgemm_k<false, false, 1><<<dim3(64, 8), 256, 0, stream>>>(
        Tokh, Tokl, nullptr, nullptr, nullptr, nullptr,
        Wsh, Wsl, in_b, nullptr, Qh, Ql, 1024, 0.18033688011112042f);
    // k -> K planes with per-batch concat row remap
    bfgemm_k<false, false, 2><<<dim3(64, 8), 256, 0, stream>>>(
        ActH, ActL, nullptr, nullptr, nullptr, nullptr,
        Wsh + (size_t)1024 * 1024, Wsl + (size_t)1024 * 1024,
        in_b + 1024, nullptr, Kh, Kl, 1024, 1.0f);
    // v^T: operands swapped (A = wv rows, "W" = act rows) -> transposed planes
    bfgemm_k<false, false, 3><<<dim3(8, 64), 256, 0, stream>>>(
        Wsh + (size_t)2048 * 1024, Wsl + (size_t)2048 * 1024,
        nullptr, nullptr, nullptr, nullptr,
        ActH, ActL, in_b + 2048, nullptr, Vth, Vtl, 1024, 1.0f);

    attn_k<<<dim3(64, 8), 512, 0, stream>>>(Qh, Ql, Kh, Kl, Vth, Vtl, Qh, Ql);

    // out_proj: ctx planes (in Qh/Ql) @ op_w -> fp32 F0
    split_k<<<1024, 256, 0, stream>>>(op_w, Wsh, Wsl, 1024 * 1024 / 4);
    bfgemm_k<false, false, 0><<<dim3(64, 8), 256, 0, stream>>>(
        Qh, Ql, nullptr, nullptr, nullptr, nullptr,
        Wsh, Wsl, op_b, F0, nullptr, nullptr, 1024, 1.0f);

    // ctx_B = LN(out_proj + tokens) -> planes (reuse K planes)
    ln_split_k<<<8192, 256, 0, stream>>>(F0, tokens, lng, lnb, Kh, Kl);

    // gate hidden = relu([tokens | ctx_B | t_emb] @ g_w1.T + b1) -> F0
    split_k<<<4, 256, 0, stream>>>(temb, Tbh, Tbl, 4096 / 4);
    split_k<<<3072, 256, 0, stream>>>(g_w1, Wsh, Wsl, 3072 * 1024 / 4);
    bfgemm_k<true, true, 0><<<dim3(64, 8), 256, 0, stream>>>(
        Tokh, Tokl, Kh, Kl, Tbh, Tbl,
        Wsh, Wsl, g_b1, F0, nullptr, nullptr, 3072, 1.0f);

    logits_k<<<2048, 256, 0, stream>>>(F0, g_w2, g_b2, e_bias, logitsb);
    router_k<<<32, 256, 0, stream>>>(logitsb, tt, out, loads);
    penalty_k<<<1, 64, 0, stream>>>(loads, out);
}

// Round 9
// 844.318 us; speedup vs baseline: 1.0444x; 1.0444x over previous
//
#include <hip/hip_runtime.h>
#include <math.h>

// Problem constants
//   B=4, NB=2048, NA=NC=1024, D=1024, E=8, H=16, HD=64, TOP_K=2
// R3 lesson: NO lambdas capturing register arrays in hot kernels (scratch spills).
// R4 lesson: transpose-store staging maps must be checked for bank collapse.
// R5: GEMMs on bf16 split-3 MFMA (hi*hi+hi*lo+lo*hi), err ~2^-16 — verified safe.
// R6: attention on split-3 MFMA. No-max softmax (scores bounded ~2.4, exp safe).
// R7 LESSON: forcing occupancy past natural reg demand -> catastrophic spill.
// R8 LESSON: swizzles must be audited mod-32 PER ACCESS WIDTH.
// R10: swapped-operand attention: S^T = mfma32(K_frag, Q_frag); exp(S^T) regs
//     ARE the P^T B-frag -> PV from regs, no P LDS. 246us @ 64 VGPR — attn runs
//     ~840 TF real (split-3 QK+PV), already m97-class. KEEP AS-IS.
// R11 LESSON: dbuf+1-barrier async GEMM at 2 blocks/CU REGRESSED: barrier drain
//     exposed with no co-resident cover.
// R12 LESSON: paired-jt mfma32 PV spilled (WRITE 48->509MB scratch signature).
//     attn has ~zero register headroom; reverted to R10 attn.
// R13: GEMMs -> m97 structure (guide: 874-912 TF at this tile): global_load_lds
//     (linear tid map, verified in R11), SINGLE-buffered 32KB LDS (4 planes),
//     2 barriers/K-step, __launch_bounds__(256,3) -> 3 blocks/CU so co-resident
//     blocks hide the stage drain (m114 wave-overlap). Staging VGPRs deleted:
//     peak live ~116 < 170 cap (audited, R7 rule).

typedef __attribute__((ext_vector_type(8))) short short8;
typedef __attribute__((ext_vector_type(4))) short sh4;
typedef __attribute__((ext_vector_type(4))) float f32x4;
typedef __attribute__((ext_vector_type(4))) unsigned int u32x4;
typedef unsigned short u16;
typedef unsigned int u32;

// ----------------------------------------------------------------------------
__global__ void zero_k(double* p) {
    if (threadIdx.x < 8) p[threadIdx.x] = 0.0;
}

// ----------------------------------------------------------------------------
// fp32 -> bf16 hi/lo split helpers (RNE)
__device__ inline u16 bf_hi(float x) {
    u32 u = __float_as_uint(x);
    u += 0x7FFFu + ((u >> 16) & 1u);
    return (u16)(u >> 16);
}
__device__ inline u16 bf_lo(float x, u16 h) {
    float hf = __uint_as_float(((u32)h) << 16);
    return bf_hi(x - hf);
}
__device__ inline u32 pack_bf(float x) {
    u32 u = __float_as_uint(x);
    u32 hi = (u + (0x7FFFu + ((u >> 16) & 1u))) >> 16;
    float hf = __uint_as_float(hi << 16);
    float d = x - hf;
    u32 u2 = __float_as_uint(d);
    u32 lo = (u2 + (0x7FFFu + ((u2 >> 16) & 1u))) >> 16;
    return (hi << 16) | lo;
}

// fast pair-pack: two fp32 -> two (hi<<16|lo) u32 via v_cvt_pk_bf16_f32 + v_perm.
__device__ inline void pack2(float p0, float p1, u32& o0, u32& o1) {
    u32 h01, l01;
    asm("v_cvt_pk_bf16_f32 %0, %1, %2" : "=v"(h01) : "v"(p0), "v"(p1));
    float d0 = p0 - __uint_as_float(h01 << 16);
    float d1 = p1 - __uint_as_float(h01 & 0xffff0000u);
    asm("v_cvt_pk_bf16_f32 %0, %1, %2" : "=v"(l01) : "v"(d0), "v"(d1));
    o0 = __builtin_amdgcn_perm(h01, l01, 0x05040100u);   // [h0|l0]
    o1 = __builtin_amdgcn_perm(h01, l01, 0x07060302u);   // [h1|l1]
}

// exp2 of 4 scores -> split-3 bf16 P^T fragments (hi, lo) + lsum accumulate.
__device__ inline void pfrag(const f32x4 s, sh4& hi, sh4& lo, float& acc) {
    float p0 = exp2f(s[0]), p1 = exp2f(s[1]), p2 = exp2f(s[2]), p3 = exp2f(s[3]);
    acc += (p0 + p1) + (p2 + p3);
    u32 h01, h23, l01, l23;
    asm("v_cvt_pk_bf16_f32 %0, %1, %2" : "=v"(h01) : "v"(p0), "v"(p1));
    asm("v_cvt_pk_bf16_f32 %0, %1, %2" : "=v"(h23) : "v"(p2), "v"(p3));
    float d0 = p0 - __uint_as_float(h01 << 16);
    float d1 = p1 - __uint_as_float(h01 & 0xffff0000u);
    float d2 = p2 - __uint_as_float(h23 << 16);
    float d3 = p3 - __uint_as_float(h23 & 0xffff0000u);
    asm("v_cvt_pk_bf16_f32 %0, %1, %2" : "=v"(l01) : "v"(d0), "v"(d1));
    asm("v_cvt_pk_bf16_f32 %0, %1, %2" : "=v"(l23) : "v"(d2), "v"(d3));
    union { u32 u[2]; sh4 s4; } H, L;
    H.u[0] = h01; H.u[1] = h23;
    L.u[0] = l01; L.u[1] = l23;
    hi = H.s4; lo = L.s4;
}

__device__ inline f32x4 mfma32(short8 a, short8 b, f32x4 c) {
    return __builtin_amdgcn_mfma_f32_16x16x32_bf16(a, b, c, 0, 0, 0);
}
__device__ inline f32x4 mfma16(sh4 a, sh4 b, f32x4 c) {
#if __has_builtin(__builtin_amdgcn_mfma_f32_16x16x16bf16_1k)
    return __builtin_amdgcn_mfma_f32_16x16x16bf16_1k(a, b, c, 0, 0, 0);
#else
    asm volatile("v_mfma_f32_16x16x16_bf16 %0, %1, %2, %0"
                 : "+v"(c) : "v"(a), "v"(b));
    return c;
#endif
}

// async global->LDS, 16B per lane. LDS dest = wave-uniform base + lane*16.
__device__ inline void async16(const u16* g, u16* l) {
    __builtin_amdgcn_global_load_lds(
        (const __attribute__((address_space(1))) unsigned int*)g,
        (__attribute__((address_space(3))) unsigned int*)l,
        16, 0, 0);
}

__global__ __launch_bounds__(256)
void split_k(const float* __restrict__ in, u16* __restrict__ hi,
             u16* __restrict__ lo, int n4) {
    int i = blockIdx.x * 256 + threadIdx.x;
    if (i >= n4) return;
    float4 x = ((const float4*)in)[i];
    ushort4 h, l;
    h.x = bf_hi(x.x); l.x = bf_lo(x.x, h.x);
    h.y = bf_hi(x.y); l.y = bf_lo(x.y, h.y);
    h.z = bf_hi(x.z); l.z = bf_lo(x.z, h.z);
    h.w = bf_hi(x.w); l.w = bf_lo(x.w, h.w);
    ((ushort4*)hi)[i] = h;
    ((ushort4*)lo)[i] = l;
}

// ----------------------------------------------------------------------------
__global__ void emb_k(const int* __restrict__ t, float* __restrict__ emb) {
    int b = blockIdx.x;
    int j = threadIdx.x; // 0..511
    float x1 = (float)(-9.210340371976184) * (float)j;
    float x2 = x1 / 511.0f;
    float freq = (float)exp((double)x2);
    float tf = (float)t[b];
    float arg = tf * freq;
    emb[b * 1024 + j]       = (float)sin((double)arg);
    emb[b * 1024 + 512 + j] = (float)cos((double)arg);
}

// ----------------------------------------------------------------------------
__global__ void te_fc_k(const float* __restrict__ in, const float* __restrict__ W,
                        const float* __restrict__ bias, float* __restrict__ out,
                        int K, int N, int do_silu) {
    int b = blockIdx.x;
    int wv = threadIdx.x >> 6, lane = threadIdx.x & 63;
    const float* inb = in + (size_t)b * K;
    int n0 = blockIdx.y * 16 + wv * 4;
    for (int q = 0; q < 4; q++) {
        int n = n0 + q;
        const float* wr = W + (size_t)n * K;
        float acc = 0.f;
        for (int c = lane * 4; c < K; c += 256) {
            float4 a  = *(const float4*)(inb + c);
            float4 w4 = *(const float4*)(wr + c);
            acc += a.x * w4.x + a.y * w4.y + a.z * w4.z + a.w * w4.w;
        }
#pragma unroll
        for (int off = 1; off < 64; off <<= 1) acc += __shfl_xor(acc, off, 64);
        if (lane == 0) {
            float x = acc + bias[n];
            out[(size_t)b * N + n] = do_silu ? (x / (1.0f + expf(-x))) : x;
        }
    }
}

// ----------------------------------------------------------------------------
// bf16 split-3 MFMA GEMM, m97 structure (R13): global_load_lds staging into a
// SINGLE 32KB LDS buffer (4 planes of 128x32), 2 barriers per K-step; 3
// blocks/CU via __launch_bounds__(256,3) so co-resident blocks hide the drain.
// C[rr,cc] = (dot(A[rr,:K], W[cc,:K]) + bias) * scale.
// OMODE: 0 = fp32 out (identity rows), 1 = bf16 hi/lo planes (identity),
//        2 = bf16 planes with KV row remap (K proj), 3 = transposed V^T planes
//        (rows = v-col, cols = act rows; bias indexed by ROW).
template<bool GATE, bool RELU, int OMODE>
__global__ __launch_bounds__(256, 3)
void bfgemm_k(const u16* __restrict__ A0h, const u16* __restrict__ A0l,
              const u16* __restrict__ A1h, const u16* __restrict__ A1l,
              const u16* __restrict__ A2h, const u16* __restrict__ A2l,
              const u16* __restrict__ Wh_g, const u16* __restrict__ Wl_g,
              const float* __restrict__ bias, float* __restrict__ C,
              u16* __restrict__ Chi, u16* __restrict__ Clo, int K, float scale)
{
    __shared__ __align__(16) u16 smem[4][4096];   // Ah, Al, Wh, Wl (128x32 each)
    const int tid = threadIdx.x;
    const int row0 = blockIdx.x * 128;
    const int col0 = blockIdx.y * 128;
    const int wv = tid >> 6;
    const int lane = tid & 63;
    const int wrow = (wv & 1) * 64;
    const int wcol = (wv >> 1) * 64;
    const int l15 = lane & 15, quad = lane >> 4;

    f32x4 acc[4][4];
#pragma unroll
    for (int i = 0; i < 4; i++)
#pragma unroll
        for (int j = 0; j < 4; j++)
            acc[i][j] = (f32x4){0.f, 0.f, 0.f, 0.f};

    const int ar0 = tid >> 2, akc = (tid & 3) * 8;   // LDS linear: tid*8 u16
    const int woff = wv * 512;                       // per-wave LDS chunk (u16)

    for (int kc = 0; kc < K; kc += 32) {
        const u16* pAh = A0h;
        const u16* pAl = A0l;
        int kk = kc;
        int tembseg = 0;
        if (GATE) {
            int seg = kc >> 10;
            if (seg == 1) { pAh = A1h; pAl = A1l; }
            else if (seg == 2) { pAh = A2h; pAl = A2l; tembseg = 1; }
            kk = kc & 1023;
        }
        const int astr = GATE ? 1024 : K;
        int g0 = row0 + ar0, g1 = row0 + ar0 + 64;
        if (GATE && tembseg) { g0 >>= 11; g1 >>= 11; }
        __syncthreads();                  // prev compute done -> LDS free
        u16* b_ = &smem[0][0] + woff;
        async16(&pAh[(size_t)g0 * astr + kk + akc], b_);
        async16(&pAh[(size_t)g1 * astr + kk + akc], b_ + 2048);
        async16(&pAl[(size_t)g0 * astr + kk + akc], b_ + 4096);
        async16(&pAl[(size_t)g1 * astr + kk + akc], b_ + 6144);
        async16(&Wh_g[(size_t)(col0 + ar0) * K + kc + akc], b_ + 8192);
        async16(&Wh_g[(size_t)(col0 + ar0 + 64) * K + kc + akc], b_ + 10240);
        async16(&Wl_g[(size_t)(col0 + ar0) * K + kc + akc], b_ + 12288);
        async16(&Wl_g[(size_t)(col0 + ar0 + 64) * K + kc + akc], b_ + 14336);
        __syncthreads();                  // vmcnt drained -> tile visible

        const u16* Ahs = &smem[0][0];
        const u16* Als = &smem[1][0];
        const u16* Whs = &smem[2][0];
        const u16* Wls = &smem[3][0];

        short8 a_h[4], a_l[4];
#pragma unroll
        for (int i = 0; i < 4; i++) {
            int r = (wrow + i * 16 + l15) * 32 + quad * 8;
            a_h[i] = *(const short8*)&Ahs[r];
            a_l[i] = *(const short8*)&Als[r];
        }
#pragma unroll
        for (int j = 0; j < 4; j++) {
            int c = (wcol + j * 16 + l15) * 32 + quad * 8;
            short8 b_h = *(const short8*)&Whs[c];
            short8 b_l = *(const short8*)&Wls[c];
#pragma unroll
            for (int i = 0; i < 4; i++) {
                acc[i][j] = __builtin_amdgcn_mfma_f32_16x16x32_bf16(a_h[i], b_h, acc[i][j], 0, 0, 0);
                acc[i][j] = __builtin_amdgcn_mfma_f32_16x16x32_bf16(a_h[i], b_l, acc[i][j], 0, 0, 0);
                acc[i][j] = __builtin_amdgcn_mfma_f32_16x16x32_bf16(a_l[i], b_h, acc[i][j], 0, 0, 0);
            }
        }
    }

#pragma unroll
    for (int i = 0; i < 4; i++) {
#pragma unroll
        for (int j = 0; j < 4; j++) {
            int cc = col0 + wcol + j * 16 + l15;
#pragma unroll
            for (int r = 0; r < 4; r++) {
                int rr = row0 + wrow + i * 16 + quad * 4 + r;
                float v = (acc[i][j][r] + ((OMODE == 3) ? bias[rr] : bias[cc])) * scale;
                if (RELU) v = fmaxf(v, 0.f);
                if (OMODE == 0) {
                    C[(size_t)rr * 1024 + cc] = v;
                } else if (OMODE == 1) {
                    u32 pk = pack_bf(v);
                    size_t a = (size_t)rr * 1024 + cc;
                    Chi[a] = (u16)(pk >> 16); Clo[a] = (u16)pk;
                } else if (OMODE == 2) {
                    int orow = ((rr >> 10) & 3) * 2048 + (rr >> 12) * 1024 + (rr & 1023);
                    u32 pk = pack_bf(v);
                    size_t a = (size_t)orow * 1024 + cc;
                    Chi[a] = (u16)(pk >> 16); Clo[a] = (u16)pk;
                } else {
                    int bb2 = (cc >> 10) & 3;
                    int key = (cc >> 12) * 1024 + (cc & 1023);
                    u32 pk = pack_bf(v);
                    size_t a = ((size_t)(bb2 * 1024 + rr)) * 2048 + key;
                    Chi[a] = (u16)(pk >> 16); Clo[a] = (u16)pk;
                }
            }
        }
    }
}

// ----------------------------------------------------------------------------
// MFMA flash attention, split-3 bf16, no-max softmax, swapped operands (R10).
// Block: 512 thr (8 waves), q-tile 256 (32 q/wave), k-tile 64, 32 k-steps.
// LDS 65536 B (2 blocks/CU): K,V tiles double-buffered, chunk-XOR swizzled.
// S^T = mfma32(A=K_frag, B=Q_frag); exp(S^T) regs are directly the P^T
// B-fragment of mfma16; O^T accumulated in regs; epilogue LDS transpose.
__global__ __launch_bounds__(512, 4)
void attn_k(const u16* Qh, const u16* Ql,
            const u16* __restrict__ Kh, const u16* __restrict__ Kl,
            const u16* __restrict__ Vh, const u16* __restrict__ Vl,
            u16* Oh, u16* Ol)
{
    __shared__ __align__(16) u16 smem[32768];   // 64 KB
    u16* Kbase = smem;              // [buf:2][plane:2][4096]
    u16* Vbase = smem + 16384;      // [buf:2][plane:2][4096]

    const int tid = threadIdx.x;
    const int w = tid >> 6, lane = tid & 63;
    const int l15 = lane & 15, quad = lane >> 4;
    const int bh = blockIdx.x, b = bh >> 4, h = bh & 15;
    const int qw = blockIdx.y * 256 + w * 32;          // local q base of this wave
    const int qrow0 = b * 2048 + qw;                    // global Q plane row base

    // Q fragments in registers: same loads as before; now used as the
    // B-operand (= Q^T) of the swapped QK^T.
    short8 qh_f[2][2], ql_f[2][2];
#pragma unroll
    for (int i = 0; i < 2; i++)
#pragma unroll
        for (int kc = 0; kc < 2; kc++) {
            size_t a = (size_t)(qrow0 + i * 16 + l15) * 1024 + h * 64 + kc * 32 + quad * 8;
            qh_f[i][kc] = *(const short8*)&Qh[a];
            ql_f[i][kc] = *(const short8*)&Ql[a];
        }

    // staging maps: linear LDS dest (wave base + lane*16); global source column
    // carries the chunk swizzle c8 ^ (row&7). 512 thr cover a 64-row tile/plane.
    const int srow = tid >> 3;                        // 0..63
    const int scsw = ((tid & 7) ^ (srow & 7)) << 3;   // swizzled u16 col
    const size_t gk_base = ((size_t)(b * 2048) + srow) * 1024 + h * 64 + scsw;
    const size_t gv_base = ((size_t)((b * 16 + h) * 64 + srow)) * 2048 + scsw;

    f32x4 o[4][2];                 // O^T accumulators: [d-tile][q-subtile]
#pragma unroll
    for (int dt = 0; dt < 4; dt++)
#pragma unroll
        for (int i = 0; i < 2; i++) o[dt][i] = (f32x4){0.f, 0.f, 0.f, 0.f};
    float lsum[2] = {0.f, 0.f};

    // prologue: stage tile 0 into buf 0
    {
        u16* kd = Kbase + w * 512;
        u16* vd = Vbase + w * 512;
        async16(&Kh[gk_base], kd);
        async16(&Kl[gk_base], kd + 4096);
        async16(&Vh[gv_base], vd);
        async16(&Vl[gv_base], vd + 4096);
    }
    __syncthreads();   // vmcnt drained before barrier -> tile 0 ready

    for (int kt = 0; kt < 32; kt++) {
        const int cur = kt & 1;
        if (kt < 31) {
            const int nxt = cur ^ 1;
            const size_t gk = gk_base + (size_t)(kt + 1) * 65536;  // +64 keys
            const size_t gv = gv_base + (size_t)(kt + 1) * 64;     // +64 key-cols
            u16* kd = Kbase + nxt * 8192 + w * 512;
            u16* vd = Vbase + nxt * 8192 + w * 512;
            async16(&Kh[gk], kd);
            async16(&Kl[gk], kd + 4096);
            async16(&Vh[gv], vd);
            async16(&Vl[gv], vd + 4096);
        }
        const u16* Ksh = Kbase + cur * 8192;
        const u16* Ksl = Ksh + 4096;
        const u16* Vsh = Vbase + cur * 8192;
        const u16* Vsl = Vsh + 4096;

#pragma unroll
        for (int jt = 0; jt < 4; jt++) {
            // swapped QK^T: st[i] holds S^T[key=jt*16+quad*4+r][q=i*16+l15]
            f32x4 st0 = (f32x4){0.f, 0.f, 0.f, 0.f};
            f32x4 st1 = (f32x4){0.f, 0.f, 0.f, 0.f};
            const int ka = (jt * 16 + l15) * 64 + ((quad ^ (l15 & 7)) << 3);
            short8 kh0 = *(const short8*)&Ksh[ka];
            short8 kh1 = *(const short8*)&Ksh[ka ^ 32];
            short8 kl0 = *(const short8*)&Ksl[ka];
            short8 kl1 = *(const short8*)&Ksl[ka ^ 32];
            st0 = mfma32(kh0, qh_f[0][0], st0);
            st0 = mfma32(kl0, qh_f[0][0], st0);
            st0 = mfma32(kh0, ql_f[0][0], st0);
            st0 = mfma32(kh1, qh_f[0][1], st0);
            st0 = mfma32(kl1, qh_f[0][1], st0);
            st0 = mfma32(kh1, ql_f[0][1], st0);
            st1 = mfma32(kh0, qh_f[1][0], st1);
            st1 = mfma32(kl0, qh_f[1][0], st1);
            st1 = mfma32(kh0, ql_f[1][0], st1);
            st1 = mfma32(kh1, qh_f[1][1], st1);
            st1 = mfma32(kl1, qh_f[1][1], st1);
            st1 = mfma32(kh1, ql_f[1][1], st1);
            // exp2 (scale folded into Q) -> P^T fragments, straight in regs
            sh4 phi0, plo0, phi1, plo1;
            pfrag(st0, phi0, plo0, lsum[0]);
            pfrag(st1, phi1, plo1, lsum[1]);
            // PV: O^T[dt][i] += V^T-frag x P^T-frag (split-3)
#pragma unroll
            for (int dt = 0; dt < 4; dt++) {
                const int va = (dt * 16 + l15) * 64
                             + (((jt * 2 + (quad >> 1)) ^ (l15 & 7)) << 3)
                             + (quad & 1) * 4;
                sh4 vvh = *(const sh4*)&Vsh[va];
                sh4 vvl = *(const sh4*)&Vsl[va];
                o[dt][0] = mfma16(vvh, phi0, o[dt][0]);
                o[dt][0] = mfma16(vvl, phi0, o[dt][0]);
                o[dt][0] = mfma16(vvh, plo0, o[dt][0]);
                o[dt][1] = mfma16(vvh, phi1, o[dt][1]);
                o[dt][1] = mfma16(vvl, phi1, o[dt][1]);
                o[dt][1] = mfma16(vvh, plo1, o[dt][1]);
            }
        }
        __syncthreads();   // all reads of buf[cur] done; DMA(kt+1) drained
    }

    // lsum: sum over k -> reduce across the 4 quads (q = i*16+l15 per lane)
#pragma unroll
    for (int i = 0; i < 2; i++) {
        float s2 = lsum[i];
        s2 += __shfl_xor(s2, 16, 64);
        s2 += __shfl_xor(s2, 32, 64);
        lsum[i] = 1.0f / s2;
    }

    // epilogue: O^T -> O via in-LDS transpose (aliases dead K/V region; the
    // final loop barrier synced all waves). Per-wave 8KB region, XOR-swizzled:
    // write b64 2 lanes/bank, read b128 8 lanes/4-bank group (floor).
    u32* otr = (u32*)smem + w * 2048;
#pragma unroll
    for (int i = 0; i < 2; i++) {
        const int q = i * 16 + l15;
        const int xm = (q & 7) << 2;
#pragma unroll
        for (int dt = 0; dt < 4; dt++) {
#pragma unroll
            for (int r = 0; r < 4; r += 2) {
                float v0 = o[dt][i][r]     * lsum[i];
                float v1 = o[dt][i][r + 1] * lsum[i];
                u32 a0, a1;
                pack2(v0, v1, a0, a1);
                const int d = dt * 16 + quad * 4 + r;
                uint2 val; val.x = a0; val.y = a1;
                *(uint2*)&otr[q * 64 + (d ^ xm)] = val;
            }
        }
    }
    // same-wave read-back (in-wave lgkm ordering suffices)
    const int qr = lane >> 1;      // 0..31
    const int dh = lane & 1;
    const size_t gq = (size_t)(qrow0 + qr) * 1024 + h * 64 + dh * 32;
#pragma unroll
    for (int g = 0; g < 4; g++) {
        const int c0 = dh * 8 + g * 2;
        const int m = qr & 7;
        uint4 x = *(const uint4*)&otr[qr * 64 + ((c0 ^ m) << 2)];
        uint4 y = *(const uint4*)&otr[qr * 64 + (((c0 + 1) ^ m) << 2)];
        union { short8 s; u32x4 u; } hh, ll;
        hh.u = (u32x4){ __builtin_amdgcn_perm(x.y, x.x, 0x07060302u),
                        __builtin_amdgcn_perm(x.w, x.z, 0x07060302u),
                        __builtin_amdgcn_perm(y.y, y.x, 0x07060302u),
                        __builtin_amdgcn_perm(y.w, y.z, 0x07060302u) };
        ll.u = (u32x4){ __builtin_amdgcn_perm(x.y, x.x, 0x05040100u),
                        __builtin_amdgcn_perm(x.w, x.z, 0x05040100u),
                        __builtin_amdgcn_perm(y.y, y.x, 0x05040100u),
                        __builtin_amdgcn_perm(y.w, y.z, 0x05040100u) };
        *(short8*)&Oh[gq + g * 8] = hh.s;
        *(short8*)&Ol[gq + g * 8] = ll.s;
    }
}

// ----------------------------------------------------------------------------
// layernorm(X + T) * g + b, emitting bf16 hi/lo planes for the gate GEMM
__global__ __launch_bounds__(256)
void ln_split_k(const float* __restrict__ X, const float* __restrict__ T,
                const float* __restrict__ g, const float* __restrict__ bta,
                u16* __restrict__ chi, u16* __restrict__ clo)
{
    __shared__ float red[8];
    int r = blockIdx.x, tid = threadIdx.x;
    size_t base = (size_t)r * 1024 + tid * 4;
    float4 x  = *(const float4*)(X + base);
    float4 tk = *(const float4*)(T + base);
    x.x += tk.x; x.y += tk.y; x.z += tk.z; x.w += tk.w;
    float s = x.x + x.y + x.z + x.w;
#pragma unroll
    for (int off = 1; off < 64; off <<= 1) s += __shfl_xor(s, off, 64);
    int wv = tid >> 6;
    if ((tid & 63) == 0) red[wv] = s;
    __syncthreads();
    float mu = (red[0] + red[1] + red[2] + red[3]) * (1.0f / 1024.0f);
    float dx0 = x.x - mu, dx1 = x.y - mu, dx2 = x.z - mu, dx3 = x.w - mu;
    float ss = dx0 * dx0 + dx1 * dx1 + dx2 * dx2 + dx3 * dx3;
#pragma unroll
    for (int off = 1; off < 64; off <<= 1) ss += __shfl_xor(ss, off, 64);
    if ((tid & 63) == 0) red[4 + wv] = ss;
    __syncthreads();
    float var = (red[4] + red[5] + red[6] + red[7]) * (1.0f / 1024.0f);
    float inv = 1.0f / sqrtf(var + 1e-5f);
    float4 gg = *(const float4*)(g + tid * 4);
    float4 bb = *(const float4*)(bta + tid * 4);
    float y0 = dx0 * inv * gg.x + bb.x;
    float y1 = dx1 * inv * gg.y + bb.y;
    float y2 = dx2 * inv * gg.z + bb.z;
    float y3 = dx3 * inv * gg.w + bb.w;
    ushort4 h, l;
    h.x = bf_hi(y0); l.x = bf_lo(y0, h.x);
    h.y = bf_hi(y1); l.y = bf_lo(y1, h.y);
    h.z = bf_hi(y2); l.z = bf_lo(y2, h.z);
    h.w = bf_hi(y3); l.w = bf_lo(y3, h.w);
    *(ushort4*)&chi[base] = h;
    *(ushort4*)&clo[base] = l;
}

// ----------------------------------------------------------------------------
__global__ __launch_bounds__(256)
void logits_k(const float* __restrict__ Hd, const float* __restrict__ W2,
              const float* __restrict__ b2, const float* __restrict__ eb,
              float* __restrict__ Lg)
{
    int gw = (blockIdx.x * 256 + threadIdx.x) >> 6;  // row 0..8191
    int lane = threadIdx.x & 63;
    const float* h = Hd + (size_t)gw * 1024;
    float4 hv[4];
#pragma unroll
    for (int j = 0; j < 4; j++) hv[j] = *(const float4*)(h + j * 256 + lane * 4);
    float res[8];
#pragma unroll
    for (int e = 0; e < 8; e++) {
        const float* w = W2 + (size_t)e * 1024;
        float acc = 0.f;
#pragma unroll
        for (int j = 0; j < 4; j++) {
            float4 w4 = *(const float4*)(w + j * 256 + lane * 4);
            acc += hv[j].x * w4.x + hv[j].y * w4.y + hv[j].z * w4.z + hv[j].w * w4.w;
        }
#pragma unroll
        for (int off = 1; off < 64; off <<= 1) acc += __shfl_xor(acc, off, 64);
        res[e] = acc;
    }
    if (lane < 8) {
        float v = res[0];
#pragma unroll
        for (int e = 1; e < 8; e++) v = (lane == e) ? res[e] : v;
        Lg[(size_t)gw * 8 + lane] = v + b2[lane] + eb[lane];
    }
}

// ----------------------------------------------------------------------------
__global__ __launch_bounds__(256)
void router_k(const float* __restrict__ Lg, const int* __restrict__ t,
              float* __restrict__ outp, double* __restrict__ loadAcc)
{
    __shared__ double wred[4][8];
    int tid = threadIdx.x;
    int r = blockIdx.x * 256 + tid;   // 0..8191
    int b = r >> 11;
    float tn  = (float)t[b] / 1000.0f;
    float tau = 0.5f + 1.5f * tn;
    float p[8];
    float mx = -INFINITY;
#pragma unroll
    for (int e = 0; e < 8; e++) { p[e] = Lg[(size_t)r * 8 + e] / tau; mx = fmaxf(mx, p[e]); }
    float sum = 0.f;
#pragma unroll
    for (int e = 0; e < 8; e++) { p[e] = expf(p[e] - mx); sum += p[e]; }
#pragma unroll
    for (int e = 0; e < 8; e++) p[e] = p[e] / sum;
#pragma unroll
    for (int e = 0; e < 8; e++) p[e] = 0.85f * p[e] + 0.01875f;   // (1-ALPHA)p + ALPHA/E
    float w = 0.1f + 0.1f * tn;
    float shared_p = fmaxf(p[0], w);
    float osum = 0.f;
#pragma unroll
    for (int e = 1; e < 8; e++) osum += p[e];
    float denom_o = fmaxf(osum, 1e-8f);
    float one_m = 1.0f - shared_p;
    p[0] = shared_p;
#pragma unroll
    for (int e = 1; e < 8; e++) p[e] = (p[e] / denom_o) * one_m;  // match np op order
    int i0 = 0; float v0 = p[0];
#pragma unroll
    for (int e = 1; e < 8; e++) if (p[e] > v0) { v0 = p[e]; i0 = e; }
    int i1 = -1; float v1 = -INFINITY;
#pragma unroll
    for (int e = 0; e < 8; e++) if (e != i0 && p[e] > v1) { v1 = p[e]; i1 = e; }
    float cap = 0.5f + 0.1f * tn;
    float dsp[8], capped[8], hr[8];
    float exsum = 0.f, hsum = 0.f;
#pragma unroll
    for (int e = 0; e < 8; e++) {
        float d = ((e == i0) ? v0 : 0.f) + ((e == i1) ? v1 : 0.f);
        float ex = fmaxf(d - cap, 0.f);
        float c = d - ex;
        float hh = fmaxf(cap - c, 0.f);
        capped[e] = c; hr[e] = hh;
        exsum += ex; hsum += hh;
    }
    float hden = fmaxf(hsum, 1e-8f);
    float dsum = 0.f;
#pragma unroll
    for (int e = 0; e < 8; e++) {
        float d = capped[e] + exsum * (hr[e] / hden);
        dsp[e] = d; dsum += d;
    }
    float cden = dsum + 1e-8f;
#pragma unroll
    for (int e = 0; e < 8; e++) {
        outp[(size_t)r * 8 + e] = dsp[e];
        outp[65536 + (size_t)r * 8 + e] = dsp[e] / cden;
    }
    int lane = tid & 63, wv = tid >> 6;
#pragma unroll
    for (int e = 0; e < 8; e++) {
        double s = (double)dsp[e];
#pragma unroll
        for (int off = 1; off < 64; off <<= 1) s += __shfl_xor(s, off, 64);
        if (lane == 0) wred[wv][e] = s;
    }
    __syncthreads();
    if (tid < 8) {
        double s = wred[0][tid] + wred[1][tid] + wred[2][tid] + wred[3][tid];
        atomicAdd(&loadAcc[tid], s);
    }
}

// ----------------------------------------------------------------------------
__global__ void penalty_k(const double* __restrict__ loadAcc, float* __restrict__ outp) {
    if (threadIdx.x == 0) {
        const float thr = (float)(2048.0 / 7.0 * 1.5);  // fair * 1.5
        float pen = 0.f;
#pragma unroll
        for (int e = 1; e < 8; e++) {
            float load = (float)(loadAcc[e] / 4.0);     // mean over B
            float x = fmaxf(load - thr, 0.f);
            pen += x * x;
        }
        outp[131072] = 0.01f * pen;
    }
}

// ----------------------------------------------------------------------------
extern "C" void kernel_launch(void* const* d_in, const int* in_sizes, int n_in,
                              void* d_out, int out_size, void* d_ws, size_t ws_size,
                              hipStream_t stream)
{
    const float* tokens = (const float*)d_in[0];
    const float* outA   = (const float*)d_in[1];
    const float* outC   = (const float*)d_in[2];
    const int*   tt     = (const int*)  d_in[3];
    const float* in_w   = (const float*)d_in[4];
    const float* in_b   = (const float*)d_in[5];
    const float* op_w   = (const float*)d_in[6];
    const float* op_b   = (const float*)d_in[7];
    const float* lng    = (const float*)d_in[8];
    const float* lnb    = (const float*)d_in[9];
    const float* te_w1  = (const float*)d_in[10];
    const float* te_b1  = (const float*)d_in[11];
    const float* te_w2  = (const float*)d_in[12];
    const float* te_b2  = (const float*)d_in[13];
    const float* g_w1   = (const float*)d_in[14];
    const float* g_b1   = (const float*)d_in[15];
    const float* g_w2   = (const float*)d_in[16];
    const float* g_b2   = (const float*)d_in[17];
    const float* e_bias = (const float*)d_in[18];
    float* out = (float*)d_out;

    float* ws = (float*)d_ws;
    const size_t NM = (size_t)8192 * 1024;
    float* F0     = ws;                  // out_proj result, then gate hidden (fp32)
    float* temb   = ws + NM;             // 4x1024 fp32
    float* embb   = temb + 4096;
    float* hte    = embb + 4096;         // 4x2048
    float* logitsb = hte + 8192;         // 8192x8
    double* loads = (double*)(logitsb + 65536);   // 8 doubles (+pad)

    u16* U = (u16*)(loads + 16);
    u16* Tokh = U;                 // tokens planes (alive whole launch)
    u16* Tokl = Tokh + NM;
    u16* ActH = Tokl + NM;         // [outA;outC] planes for K/V GEMMs
    u16* ActL = ActH + NM;
    u16* Qh   = ActL + NM;         // Q planes -> attn ctx planes (block-disjoint alias)
    u16* Ql   = Qh + NM;
    u16* Kh   = Ql + NM;           // K planes -> later LN(ctx_B) planes
    u16* Kl   = Kh + NM;
    u16* Vth  = Kl + NM;           // V^T planes [b][h][d][2048]
    u16* Vtl  = Vth + NM;
    u16* Wsh  = Vtl + NM;          // weight planes (up to 3M elems)
    u16* Wsl  = Wsh + (size_t)3 * 1024 * 1024;
    u16* Tbh  = Wsl + (size_t)3 * 1024 * 1024;   // temb planes, 4096
    u16* Tbl  = Tbh + 4096;

    zero_k<<<1, 64, 0, stream>>>(loads);
    emb_k<<<4, 512, 0, stream>>>(tt, embb);
    te_fc_k<<<dim3(4, 128), 256, 0, stream>>>(embb, te_w1, te_b1, hte, 1024, 2048, 1);
    te_fc_k<<<dim3(4, 64),  256, 0, stream>>>(hte,  te_w2, te_b2, temb, 2048, 1024, 0);

    split_k<<<8192, 256, 0, stream>>>(tokens, Tokh, Tokl, 8192 * 1024 / 4);
    split_k<<<3072, 256, 0, stream>>>(in_w, Wsh, Wsl, 3 * 1024 * 1024 / 4);
    split_k<<<4096, 256, 0, stream>>>(outA, ActH, ActL, 4096 * 1024 / 4);
    split_k<<<4096, 256, 0, stream>>>(outC, ActH + (size_t)4096 * 1024,
                                      ActL + (size_t)4096 * 1024, 4096 * 1024 / 4);

    // q = (tokens @ wq.T + bq) * (0.125*log2e) -> Q planes (softmax scale folded)
    bfgemm_k<false, false, 1><<<dim3(64, 8), 256, 0, stream>>>(
        Tokh, Tokl, nullptr, nullptr, nullptr, nullptr,
        Wsh, Wsl, in_b, nullptr, Qh, Ql, 1024, 0.18033688011112042f);
    // k -> K planes with per-batch concat row remap
    bfgemm_k<false, false, 2><<<dim3(64, 8), 256, 0, stream>>>(
        ActH, ActL, nullptr, nullptr, nullptr, nullptr,
        Wsh + (size_t)1024 * 1024, Wsl + (size_t)1024 * 1024,
        in_b + 1024, nullptr, Kh, Kl, 1024, 1.0f);
    // v^T: operands swapped (A = wv rows, "W" = act rows) -> transposed planes
    bfgemm_k<false, false, 3><<<dim3(8, 64), 256, 0, stream>>>(
        Wsh + (size_t)2048 * 1024, Wsl + (size_t)2048 * 1024,
        nullptr, nullptr, nullptr, nullptr,
        ActH, ActL, in_b + 2048, nullptr, Vth, Vtl, 1024, 1.0f);

    attn_k<<<dim3(64, 8), 512, 0, stream>>>(Qh, Ql, Kh, Kl, Vth, Vtl, Qh, Ql);

    // out_proj: ctx planes (in Qh/Ql) @ op_w -> fp32 F0
    split_k<<<1024, 256, 0, stream>>>(op_w, Wsh, Wsl, 1024 * 1024 / 4);
    bfgemm_k<false, false, 0><<<dim3(64, 8), 256, 0, stream>>>(
        Qh, Ql, nullptr, nullptr, nullptr, nullptr,
        Wsh, Wsl, op_b, F0, nullptr, nullptr, 1024, 1.0f);

    // ctx_B = LN(out_proj + tokens) -> planes (reuse K planes)
    ln_split_k<<<8192, 256, 0, stream>>>(F0, tokens, lng, lnb, Kh, Kl);

    // gate hidden = relu([tokens | ctx_B | t_emb] @ g_w1.T + b1) -> F0
    split_k<<<4, 256, 0, stream>>>(temb, Tbh, Tbl, 4096 / 4);
    split_k<<<3072, 256, 0, stream>>>(g_w1, Wsh, Wsl, 3072 * 1024 / 4);
    bfgemm_k<true, true, 0><<<dim3(64, 8), 256, 0, stream>>>(
        Tokh, Tokl, Kh, Kl, Tbh, Tbl,
        Wsh, Wsl, g_b1, F0, nullptr, nullptr, 3072, 1.0f);

    logits_k<<<2048, 256, 0, stream>>>(F0, g_w2, g_b2, e_bias, logitsb);
    router_k<<<32, 256, 0, stream>>>(logitsb, tt, out, loads);
    penalty_k<<<1, 64, 0, stream>>>(loads, out);
}